// Round 12
// baseline (316.902 us; speedup 1.0000x reference)
//
#include <hip/hip_runtime.h>

typedef __bf16 bf16;
typedef __attribute__((ext_vector_type(8))) bf16 bf16x8;
typedef __attribute__((ext_vector_type(4))) float f32x4;

// async global->LDS (LDS dest is wave-uniform base + lane*16)
#define GLDS16(g, l) __builtin_amdgcn_global_load_lds( \
    (const __attribute__((address_space(1))) void*)(g), \
    (__attribute__((address_space(3))) void*)(l), 16, 0, 0)

// log2(e)/sqrt(128): folded into q at the QKV epilogue so softmax uses exp2 directly
#define QSCALE 0.12751744f

static __device__ __forceinline__ f32x4 MFMA(bf16x8 a, bf16x8 b, f32x4 c) {
    return __builtin_amdgcn_mfma_f32_16x16x32_bf16(a, b, c, 0, 0, 0);
}

// ---------------------------------------------------------------- convert f32->bf16
__global__ __launch_bounds__(256) void convert_kernel(
    const float* __restrict__ x, const float* __restrict__ wq,
    const float* __restrict__ wk, const float* __restrict__ wv,
    const float* __restrict__ wp,
    bf16* __restrict__ xb, bf16* __restrict__ wqkvb, bf16* __restrict__ wpb)
{
    int bid = blockIdx.x;
    const float* src; bf16* dst; int base;
    if (bid < 4096)      { src = x;  dst = xb;              base = bid * 2048; }
    else if (bid < 4608) { src = wq; dst = wqkvb;           base = (bid - 4096) * 2048; }
    else if (bid < 5120) { src = wk; dst = wqkvb + 1048576; base = (bid - 4608) * 2048; }
    else if (bid < 5632) { src = wv; dst = wqkvb + 2097152; base = (bid - 5120) * 2048; }
    else                 { src = wp; dst = wpb;             base = (bid - 5632) * 2048; }
    int i = base + threadIdx.x * 8;
    const f32x4* s4 = (const f32x4*)(src + i);
    f32x4 a = s4[0], c = s4[1];
    bf16x8 v;
    #pragma unroll
    for (int e = 0; e < 4; ++e) { v[e] = (bf16)a[e]; v[e + 4] = (bf16)c[e]; }
    *(bf16x8*)(dst + i) = v;
}

// ---------------------------------------------------------------- barrier-free GEMM
// v6: NO LDS, NO barriers. Rationale: per-SIMD MFMA throughput is ~19.4 cyc per
// 16x16x32 MFMA, so one wave's 16-MFMA step = ~310 SIMD-cyc > L2 latency
// (~200 cyc): 2-3 free-running waves/SIMD hide VMEM latency in REGISTERS.
// Intra-block operand reuse was only 2x (L1/L2 serve it); the barriered LDS
// pipeline forced lock-step load bursts -- 6 variants all pinned at ~21%
// MfmaUtil. Per-wave 64x64 out, BK=32 steps, fragments loaded global->VGPR
// (16B/lane, 64B per 4-lane group), manual x2 unroll with NAMED double-buffer
// regs (rule #20), compiler-scheduled waitcnts.
// MODE 0: QKV epilogue (q scaled, k, v transposed per head); MODE 1: f32+bias.
template <int MODE, int NTN>
__global__ __launch_bounds__(256, 3) void gemmd(
    const bf16* __restrict__ A, const bf16* __restrict__ B,
    const float* __restrict__ bias0, const float* __restrict__ bias1,
    const float* __restrict__ bias2,
    bf16* __restrict__ q_out, bf16* __restrict__ k_out, bf16* __restrict__ vt_out,
    float* __restrict__ f_out)
{
    constexpr int K = 1024;
    constexpr int NWG = 64 * NTN;
    const int tid = threadIdx.x;
    const int lane = tid & 63;
    const int wid = tid >> 6;
    const int wr = wid >> 1, wc = wid & 1;
    const int l15 = lane & 15, l4 = lane >> 4;

    // bijective XCD chunk swizzle (NWG % 8 == 0)
    const int g = blockIdx.x;
    const int lin = (g & 7) * (NWG / 8) + (g >> 3);
    const int m0 = (lin / NTN) * 128, n0 = (lin % NTN) * 128;

    // per-lane fragment base pointers: row = m0 + wr*64 + f*16 + l15, k = l4*8
    const bf16* pA = A + (size_t)(m0 + wr * 64 + l15) * K + l4 * 8;
    const bf16* pB = B + (size_t)(n0 + wc * 64 + l15) * K + l4 * 8;
    #define LA(f, t) (*(const bf16x8*)(pA + (size_t)(f) * 16 * K + (t) * 32))
    #define LB(j, t) (*(const bf16x8*)(pB + (size_t)(j) * 16 * K + (t) * 32))

    f32x4 acc[4][4];
    #pragma unroll
    for (int f = 0; f < 4; ++f)
        #pragma unroll
        for (int j = 0; j < 4; ++j)
            #pragma unroll
            for (int e = 0; e < 4; ++e) acc[f][j][e] = 0.f;

    bf16x8 a0[4], b0[4], a1[4], b1[4];
    #pragma unroll
    for (int f = 0; f < 4; ++f) { a0[f] = LA(f, 0); b0[f] = LB(f, 0); }

    for (int t = 0; t < 32; t += 2) {
        // issue loads for step t+1 (always valid: t <= 30)
        #pragma unroll
        for (int f = 0; f < 4; ++f) { a1[f] = LA(f, t + 1); b1[f] = LB(f, t + 1); }
        __builtin_amdgcn_s_setprio(1);
        #pragma unroll
        for (int f = 0; f < 4; ++f)
            #pragma unroll
            for (int j = 0; j < 4; ++j)
                acc[f][j] = MFMA(a0[f], b0[j], acc[f][j]);
        __builtin_amdgcn_s_setprio(0);
        // issue loads for step t+2 (invalid only at t == 30)
        if (t + 2 < 32) {
            #pragma unroll
            for (int f = 0; f < 4; ++f) { a0[f] = LA(f, t + 2); b0[f] = LB(f, t + 2); }
        }
        __builtin_amdgcn_s_setprio(1);
        #pragma unroll
        for (int f = 0; f < 4; ++f)
            #pragma unroll
            for (int j = 0; j < 4; ++j)
                acc[f][j] = MFMA(a1[f], b1[j], acc[f][j]);
        __builtin_amdgcn_s_setprio(0);
    }
    #undef LA
    #undef LB

    // epilogue: C/D layout col = lane&15, row = (lane>>4)*4 + reg  [m89-verified]
    #pragma unroll
    for (int f = 0; f < 4; ++f) {
        #pragma unroll
        for (int j = 0; j < 4; ++j) {
            #pragma unroll
            for (int r = 0; r < 4; ++r) {
                int m = m0 + wr * 64 + f * 16 + l4 * 4 + r;
                int n = n0 + wc * 64 + j * 16 + l15;
                float v = acc[f][j][r];
                if (MODE == 0) {
                    if (n0 < 1024) {
                        q_out[m * 1024 + n] = (bf16)((v + bias0[n]) * QSCALE);
                    } else if (n0 < 2048) {
                        int nn = n - 1024;
                        k_out[m * 1024 + nn] = (bf16)(v + bias1[nn]);
                    } else {
                        int nn = n - 2048;
                        int hl = nn >> 7, d = nn & 127;
                        int bb = m >> 10, tt = m & 1023;
                        vt_out[((bb * 8 + hl) * 128 + d) * 1024 + tt] = (bf16)(v + bias2[nn]);
                    }
                } else {
                    f_out[m * 1024 + n] = v + bias0[n];
                }
            }
        }
    }
}

// ---------------------------------------------------------------- flash attention v4
// grid: 512 = B(8)*H(8)*(T/128); 4 waves/block, each wave owns 32 q-rows.
// QBLK=128 (bytes/MFMA 0.56 KB), un-subtracted softmax, dbuf single-barrier,
// setprio. LDS 80 KiB -> 2 blocks/CU. (unchanged from R10 -- measured good)
__global__ __launch_bounds__(256, 2) void attn_kernel(
    const bf16* __restrict__ qb, const bf16* __restrict__ kb,
    const bf16* __restrict__ vtb, const int* __restrict__ mask,
    bf16* __restrict__ yb)
{
    const int tid = threadIdx.x;
    const int lane = tid & 63;
    const int wid = tid >> 6;
    const int g = blockIdx.x;
    const int orig = (g & 7) * 64 + (g >> 3);   // bijective XCD swizzle (512 = 8*64)
    const int bh = orig >> 3;
    const int qt = orig & 7;
    const int b = bh >> 3;
    const int h = bh & 7;
    const int m0 = b * 1024 + qt * 128;
    const int l15 = lane & 15, l4 = lane >> 4;

    __shared__ __align__(16) char smem[81920];
    auto stageKV = [&](int bufKV, int kt) {
        char* Kb = smem + bufKV * 16384;
        char* Vb = smem + 32768 + bufKV * 16384;
        #pragma unroll
        for (int n = 0; n < 4; ++n)
            GLDS16(kb + (b * 1024 + kt + n * 16 + (tid >> 4)) * 1024 + h * 128 +
                       (((tid & 15) ^ ((tid >> 4) & 7)) * 8),
                   Kb + n * 4096 + tid * 16);
        #pragma unroll
        for (int n = 0; n < 4; ++n)
            GLDS16(vtb + (bh * 128 + n * 32 + (tid >> 3)) * 1024 + kt +
                       (((tid & 7) ^ ((tid >> 3) & 7)) * 8),
                   Vb + n * 4096 + tid * 16);
    };

    bf16x8 qf[2][4];
    #pragma unroll
    for (int i = 0; i < 2; ++i)
        #pragma unroll
        for (int kc = 0; kc < 4; ++kc)
            qf[i][kc] = *(const bf16x8*)(qb +
                (m0 + wid * 32 + i * 16 + l15) * 1024 + h * 128 + kc * 32 + l4 * 8);

    f32x4 o[2][8];
    #pragma unroll
    for (int i = 0; i < 2; ++i)
        #pragma unroll
        for (int jd = 0; jd < 8; ++jd)
            #pragma unroll
            for (int e = 0; e < 4; ++e) o[i][jd][e] = 0.f;
    float l_run[2][4];
    #pragma unroll
    for (int i = 0; i < 2; ++i)
        #pragma unroll
        for (int r = 0; r < 4; ++r) l_run[i][r] = 0.f;

    stageKV(0, 0);
    __syncthreads();

    for (int t = 0; t < 16; ++t) {
        const int buf = t & 1;
        const int kt = t * 64;
        if (t + 1 < 16) stageKV(buf ^ 1, kt + 64);   // issue next K/V FIRST

        int mv[4];
        #pragma unroll
        for (int j = 0; j < 4; ++j)
            mv[j] = mask[b * 1024 + kt + j * 16 + l15];

        const char* Ks = smem + buf * 16384;
        const char* Vs = smem + 32768 + buf * 16384;

        f32x4 s[2][4];
        #pragma unroll
        for (int i = 0; i < 2; ++i)
            #pragma unroll
            for (int j = 0; j < 4; ++j)
                #pragma unroll
                for (int e = 0; e < 4; ++e) s[i][j][e] = 0.f;
        #pragma unroll
        for (int kc = 0; kc < 4; ++kc) {
            bf16x8 kf[4];
            #pragma unroll
            for (int j = 0; j < 4; ++j)
                kf[j] = *(const bf16x8*)(Ks + (j * 16 + l15) * 256 +
                    (((kc * 4 + l4) ^ (lane & 7)) * 16));
            __builtin_amdgcn_s_setprio(1);
            #pragma unroll
            for (int i = 0; i < 2; ++i)
                #pragma unroll
                for (int j = 0; j < 4; ++j)
                    s[i][j] = MFMA(qf[i][kc], kf[j], s[i][j]);
            __builtin_amdgcn_s_setprio(0);
        }

        #pragma unroll
        for (int i = 0; i < 2; ++i)
            #pragma unroll
            for (int j = 0; j < 4; ++j) {
                if (mv[j] == 0) {
                    #pragma unroll
                    for (int e = 0; e < 4; ++e) s[i][j][e] = -1e30f;
                }
                #pragma unroll
                for (int r = 0; r < 4; ++r) {
                    float p = __builtin_amdgcn_exp2f(s[i][j][r]);
                    s[i][j][r] = p;
                    l_run[i][r] += p;
                }
            }

        #pragma unroll
        for (int i = 0; i < 2; ++i)
            #pragma unroll
            for (int j = 0; j < 4; ++j)
                #pragma unroll
                for (int r = 0; r < 4; ++r) {
                    int row = i * 16 + l4 * 4 + r;
                    int col = j * 16 + l15;
                    *(bf16*)(smem + 65536 + wid * 4096 + row * 128 +
                             (((col >> 3) ^ (row & 7)) * 16) + (col & 7) * 2) =
                        (bf16)s[i][j][r];
                }

        #pragma unroll
        for (int k2 = 0; k2 < 2; ++k2) {
            bf16x8 pa[2];
            #pragma unroll
            for (int i = 0; i < 2; ++i)
                pa[i] = *(const bf16x8*)(smem + 65536 + wid * 4096 +
                    (i * 16 + l15) * 128 + (((k2 * 4 + l4) ^ (l15 & 7)) * 16));
            __builtin_amdgcn_s_setprio(1);
            #pragma unroll
            for (int jd = 0; jd < 8; ++jd) {
                bf16x8 vf = *(const bf16x8*)(Vs + (jd * 16 + l15) * 128 +
                    (((k2 * 4 + l4) ^ (l15 & 7)) * 16));
                o[0][jd] = MFMA(pa[0], vf, o[0][jd]);
                o[1][jd] = MFMA(pa[1], vf, o[1][jd]);
            }
            __builtin_amdgcn_s_setprio(0);
        }
        __syncthreads();
    }

    #pragma unroll
    for (int off = 8; off >= 1; off >>= 1)
        #pragma unroll
        for (int i = 0; i < 2; ++i)
            #pragma unroll
            for (int r = 0; r < 4; ++r) l_run[i][r] += __shfl_xor(l_run[i][r], off);
    #pragma unroll
    for (int i = 0; i < 2; ++i) {
        float inv[4];
        #pragma unroll
        for (int r = 0; r < 4; ++r) inv[r] = 1.0f / fmaxf(l_run[i][r], 1e-30f);
        #pragma unroll
        for (int jd = 0; jd < 8; ++jd)
            #pragma unroll
            for (int r = 0; r < 4; ++r)
                yb[(m0 + wid * 32 + i * 16 + l4 * 4 + r) * 1024 +
                   h * 128 + jd * 16 + l15] = (bf16)(o[i][jd][r] * inv[r]);
    }
}

// ---------------------------------------------------------------- launch
extern "C" void kernel_launch(void* const* d_in, const int* in_sizes, int n_in,
                              void* d_out, int out_size, void* d_ws, size_t ws_size,
                              hipStream_t stream)
{
    (void)in_sizes; (void)n_in; (void)out_size; (void)ws_size;
    const float* x  = (const float*)d_in[0];
    const int* mask = (const int*)d_in[1];
    const float* Wq = (const float*)d_in[2];
    const float* bq = (const float*)d_in[3];
    const float* Wk = (const float*)d_in[4];
    const float* bk = (const float*)d_in[5];
    const float* Wv = (const float*)d_in[6];
    const float* bv = (const float*)d_in[7];
    const float* Wp = (const float*)d_in[8];
    const float* bp = (const float*)d_in[9];
    float* out = (float*)d_out;

    char* ws = (char*)d_ws;
    bf16* xb    = (bf16*)(ws);                      // 16 MB  x bf16 (8192 x 1024)
    bf16* wqkvb = (bf16*)(ws + (16u << 20));        //  6 MB  [Wq;Wk;Wv]
    bf16* wpb   = (bf16*)(ws + (22u << 20));        //  2 MB  Wp
    bf16* qbuf  = (bf16*)(ws + (24u << 20));        // 16 MB  q (scaled)
    bf16* kbuf  = (bf16*)(ws + (40u << 20));        // 16 MB  k
    bf16* vtb   = (bf16*)(ws + (56u << 20));        // 16 MB  v^T per (b,h)
    bf16* ybuf  = (bf16*)(ws + (72u << 20));        // 16 MB  attention out

    convert_kernel<<<6144, 256, 0, stream>>>(x, Wq, Wk, Wv, Wp, xb, wqkvb, wpb);
    gemmd<0, 24><<<1536, 256, 0, stream>>>(xb, wqkvb, bq, bk, bv,
                                           qbuf, kbuf, vtb, nullptr);
    attn_kernel<<<512, 256, 0, stream>>>(qbuf, kbuf, vtb, mask, ybuf);
    gemmd<1, 8><<<512, 256, 0, stream>>>(ybuf, wpb, bp, nullptr, nullptr,
                                         nullptr, nullptr, nullptr, out);
}

// Round 13
// 191.832 us; speedup vs baseline: 1.6520x; 1.6520x over previous
//
#include <hip/hip_runtime.h>

typedef __bf16 bf16;
typedef __attribute__((ext_vector_type(8))) bf16 bf16x8;
typedef __attribute__((ext_vector_type(4))) float f32x4;

// async global->LDS (LDS dest is wave-uniform base + lane*16)
#define GLDS16(g, l) __builtin_amdgcn_global_load_lds( \
    (const __attribute__((address_space(1))) void*)(g), \
    (__attribute__((address_space(3))) void*)(l), 16, 0, 0)

// log2(e)/sqrt(128): folded into q at the QKV epilogue so softmax uses exp2 directly
#define QSCALE 0.12751744f

static __device__ __forceinline__ f32x4 MFMA(bf16x8 a, bf16x8 b, f32x4 c) {
    return __builtin_amdgcn_mfma_f32_16x16x32_bf16(a, b, c, 0, 0, 0);
}

// ---------------------------------------------------------------- convert f32->bf16
__global__ __launch_bounds__(256) void convert_kernel(
    const float* __restrict__ x, const float* __restrict__ wq,
    const float* __restrict__ wk, const float* __restrict__ wv,
    const float* __restrict__ wp,
    bf16* __restrict__ xb, bf16* __restrict__ wqkvb, bf16* __restrict__ wpb)
{
    int bid = blockIdx.x;
    const float* src; bf16* dst; int base;
    if (bid < 4096)      { src = x;  dst = xb;              base = bid * 2048; }
    else if (bid < 4608) { src = wq; dst = wqkvb;           base = (bid - 4096) * 2048; }
    else if (bid < 5120) { src = wk; dst = wqkvb + 1048576; base = (bid - 4608) * 2048; }
    else if (bid < 5632) { src = wv; dst = wqkvb + 2097152; base = (bid - 5120) * 2048; }
    else                 { src = wp; dst = wpb;             base = (bid - 5632) * 2048; }
    int i = base + threadIdx.x * 8;
    const f32x4* s4 = (const f32x4*)(src + i);
    f32x4 a = s4[0], c = s4[1];
    bf16x8 v;
    #pragma unroll
    for (int e = 0; e < 4; ++e) { v[e] = (bf16)a[e]; v[e + 4] = (bf16)c[e]; }
    *(bf16x8*)(dst + i) = v;
}

// ---------------------------------------------------------------- fat-wave GEMM
// v7: attack bytes/MFMA, the invariant that pinned 7 schedule variants at
// 20-23% MfmaUtil (LDS read port 2.5x oversubscribed at 0.5 KB/MFMA).
// Per-wave output 64x128 (acc 4x8): 12 ds_read_b128 feed 32 MFMA =
// 0.375 KB/MFMA -> LDS port demand ~4.4 cyc/MFMA ~ balanced w/ 4.85 MFMA pipe.
// BM=BN=128, 2 waves/block (128 thr), BK=32, dbuf LDS 32 KiB -> 4 blocks/CU
// (2 waves/SIMD). Stage-first + ONE __syncthreads per iter (R7-proven).
// Paired-row LDS layout (R8, measured 0 conflicts): 128B line L holds rows
// {2L,2L+1}; 16B slot phys = ((row&1)*4 + kchunk) ^ (L&7). Swizzle folded into
// the GLOBAL source address; GLDS dest stays tid-linear (rule #21).
// MODE 0: QKV epilogue (q scaled, k, v transposed per head); MODE 1: f32+bias.
template <int MODE, int NTN>
__global__ __launch_bounds__(128, 2) void gemm2(
    const bf16* __restrict__ A, const bf16* __restrict__ B,
    const float* __restrict__ bias0, const float* __restrict__ bias1,
    const float* __restrict__ bias2,
    bf16* __restrict__ q_out, bf16* __restrict__ k_out, bf16* __restrict__ vt_out,
    float* __restrict__ f_out)
{
    constexpr int K = 1024;
    constexpr int NT = K / 32;        // 32 K-tiles
    constexpr int NWG = 64 * NTN;
    const int tid = threadIdx.x;      // 0..127
    const int lane = tid & 63;
    const int wid = tid >> 6;         // 0..1 (m-half)
    const int l15 = lane & 15, l4 = lane >> 4;

    // bijective XCD chunk swizzle (NWG % 8 == 0)
    const int g = blockIdx.x;
    const int lin = (g & 7) * (NWG / 8) + (g >> 3);
    const int m0 = (lin / NTN) * 128, n0 = (lin % NTN) * 128;

    __shared__ __align__(16) bf16 lds[2][2][4096];  // [buf][A,B][64 lines x 64 elems]

    // staging (128 thr x 4 calls per matrix): call c -> line L = c*16 + (tid>>3),
    // phys slot tid&7. Logical q = (tid&7) ^ (L&7) ((L&7) is c-invariant since
    // c*16 % 8 == 0): row = 2L + (q>>2) = c*32 + rb, kchunk = q&3.
    const int qq = (tid & 7) ^ ((tid >> 3) & 7);
    const int rb = 2 * (tid >> 3) + (qq >> 2);
    const int cc = qq & 3;
    const bf16* aB = A + (size_t)(m0 + rb) * K + cc * 8;
    const bf16* bB = B + (size_t)(n0 + rb) * K + cc * 8;
    auto stage = [&](int buf, int t) {
        #pragma unroll
        for (int c = 0; c < 4; ++c)
            GLDS16(aB + (size_t)(c * 32) * K + t * 32, &lds[buf][0][c * 1024 + tid * 8]);
        #pragma unroll
        for (int c = 0; c < 4; ++c)
            GLDS16(bB + (size_t)(c * 32) * K + t * 32, &lds[buf][1][c * 1024 + tid * 8]);
    };

    // frag read: row = base + f*16 + l15, kchunk = l4:
    //   line = base/2 + f*8 + (l15>>1); phys = ((l15&1)*4 + l4) ^ ((l15>>1)&7)
    const int physc = (((l15 & 1) * 4 + l4) ^ ((l15 >> 1) & 7)) * 16;
    const int aoff = (wid * 32 + (l15 >> 1)) * 128 + physc;
    const int boff = (l15 >> 1) * 128 + physc;
    #define RA(buf, f) (*(const bf16x8*)((const char*)lds[buf][0] + aoff + (f) * 1024))
    #define RB(buf, j) (*(const bf16x8*)((const char*)lds[buf][1] + boff + (j) * 1024))

    f32x4 acc[4][8];
    #pragma unroll
    for (int f = 0; f < 4; ++f)
        #pragma unroll
        for (int j = 0; j < 8; ++j)
            #pragma unroll
            for (int e = 0; e < 4; ++e) acc[f][j][e] = 0.f;

    stage(0, 0);
    __syncthreads();

    for (int t = 0; t < NT; ++t) {
        const int buf = t & 1;
        if (t + 1 < NT) stage(buf ^ 1, t + 1);   // issue next-tile loads FIRST
        bf16x8 af[4], bfr[8];
        #pragma unroll
        for (int f = 0; f < 4; ++f) af[f] = RA(buf, f);
        #pragma unroll
        for (int j = 0; j < 8; ++j) bfr[j] = RB(buf, j);
        __builtin_amdgcn_s_setprio(1);
        #pragma unroll
        for (int f = 0; f < 4; ++f)
            #pragma unroll
            for (int j = 0; j < 8; ++j)
                acc[f][j] = MFMA(af[f], bfr[j], acc[f][j]);
        __builtin_amdgcn_s_setprio(0);
        __syncthreads();   // drains vmcnt (stage had the whole phase to land)
    }
    #undef RA
    #undef RB

    // epilogue: C/D layout col = lane&15, row = (lane>>4)*4 + reg  [m89-verified]
    #pragma unroll
    for (int f = 0; f < 4; ++f) {
        #pragma unroll
        for (int j = 0; j < 8; ++j) {
            #pragma unroll
            for (int r = 0; r < 4; ++r) {
                int m = m0 + wid * 64 + f * 16 + l4 * 4 + r;
                int n = n0 + j * 16 + l15;
                float v = acc[f][j][r];
                if (MODE == 0) {
                    if (n0 < 1024) {
                        q_out[m * 1024 + n] = (bf16)((v + bias0[n]) * QSCALE);
                    } else if (n0 < 2048) {
                        int nn = n - 1024;
                        k_out[m * 1024 + nn] = (bf16)(v + bias1[nn]);
                    } else {
                        int nn = n - 2048;
                        int hl = nn >> 7, d = nn & 127;
                        int bb = m >> 10, tt = m & 1023;
                        vt_out[((bb * 8 + hl) * 128 + d) * 1024 + tt] = (bf16)(v + bias2[nn]);
                    }
                } else {
                    f_out[m * 1024 + n] = v + bias0[n];
                }
            }
        }
    }
}

// ---------------------------------------------------------------- flash attention v4
// grid: 512 = B(8)*H(8)*(T/128); 4 waves/block, each wave owns 32 q-rows.
// QBLK=128 (bytes/MFMA 0.56 KB), un-subtracted softmax, dbuf single-barrier,
// setprio. LDS 80 KiB -> 2 blocks/CU. (unchanged from R10 -- measured good)
__global__ __launch_bounds__(256, 2) void attn_kernel(
    const bf16* __restrict__ qb, const bf16* __restrict__ kb,
    const bf16* __restrict__ vtb, const int* __restrict__ mask,
    bf16* __restrict__ yb)
{
    const int tid = threadIdx.x;
    const int lane = tid & 63;
    const int wid = tid >> 6;
    const int g = blockIdx.x;
    const int orig = (g & 7) * 64 + (g >> 3);   // bijective XCD swizzle (512 = 8*64)
    const int bh = orig >> 3;
    const int qt = orig & 7;
    const int b = bh >> 3;
    const int h = bh & 7;
    const int m0 = b * 1024 + qt * 128;
    const int l15 = lane & 15, l4 = lane >> 4;

    __shared__ __align__(16) char smem[81920];
    auto stageKV = [&](int bufKV, int kt) {
        char* Kb = smem + bufKV * 16384;
        char* Vb = smem + 32768 + bufKV * 16384;
        #pragma unroll
        for (int n = 0; n < 4; ++n)
            GLDS16(kb + (b * 1024 + kt + n * 16 + (tid >> 4)) * 1024 + h * 128 +
                       (((tid & 15) ^ ((tid >> 4) & 7)) * 8),
                   Kb + n * 4096 + tid * 16);
        #pragma unroll
        for (int n = 0; n < 4; ++n)
            GLDS16(vtb + (bh * 128 + n * 32 + (tid >> 3)) * 1024 + kt +
                       (((tid & 7) ^ ((tid >> 3) & 7)) * 8),
                   Vb + n * 4096 + tid * 16);
    };

    bf16x8 qf[2][4];
    #pragma unroll
    for (int i = 0; i < 2; ++i)
        #pragma unroll
        for (int kc = 0; kc < 4; ++kc)
            qf[i][kc] = *(const bf16x8*)(qb +
                (m0 + wid * 32 + i * 16 + l15) * 1024 + h * 128 + kc * 32 + l4 * 8);

    f32x4 o[2][8];
    #pragma unroll
    for (int i = 0; i < 2; ++i)
        #pragma unroll
        for (int jd = 0; jd < 8; ++jd)
            #pragma unroll
            for (int e = 0; e < 4; ++e) o[i][jd][e] = 0.f;
    float l_run[2][4];
    #pragma unroll
    for (int i = 0; i < 2; ++i)
        #pragma unroll
        for (int r = 0; r < 4; ++r) l_run[i][r] = 0.f;

    stageKV(0, 0);
    __syncthreads();

    for (int t = 0; t < 16; ++t) {
        const int buf = t & 1;
        const int kt = t * 64;
        if (t + 1 < 16) stageKV(buf ^ 1, kt + 64);   // issue next K/V FIRST

        int mv[4];
        #pragma unroll
        for (int j = 0; j < 4; ++j)
            mv[j] = mask[b * 1024 + kt + j * 16 + l15];

        const char* Ks = smem + buf * 16384;
        const char* Vs = smem + 32768 + buf * 16384;

        f32x4 s[2][4];
        #pragma unroll
        for (int i = 0; i < 2; ++i)
            #pragma unroll
            for (int j = 0; j < 4; ++j)
                #pragma unroll
                for (int e = 0; e < 4; ++e) s[i][j][e] = 0.f;
        #pragma unroll
        for (int kc = 0; kc < 4; ++kc) {
            bf16x8 kf[4];
            #pragma unroll
            for (int j = 0; j < 4; ++j)
                kf[j] = *(const bf16x8*)(Ks + (j * 16 + l15) * 256 +
                    (((kc * 4 + l4) ^ (lane & 7)) * 16));
            __builtin_amdgcn_s_setprio(1);
            #pragma unroll
            for (int i = 0; i < 2; ++i)
                #pragma unroll
                for (int j = 0; j < 4; ++j)
                    s[i][j] = MFMA(qf[i][kc], kf[j], s[i][j]);
            __builtin_amdgcn_s_setprio(0);
        }

        #pragma unroll
        for (int i = 0; i < 2; ++i)
            #pragma unroll
            for (int j = 0; j < 4; ++j) {
                if (mv[j] == 0) {
                    #pragma unroll
                    for (int e = 0; e < 4; ++e) s[i][j][e] = -1e30f;
                }
                #pragma unroll
                for (int r = 0; r < 4; ++r) {
                    float p = __builtin_amdgcn_exp2f(s[i][j][r]);
                    s[i][j][r] = p;
                    l_run[i][r] += p;
                }
            }

        #pragma unroll
        for (int i = 0; i < 2; ++i)
            #pragma unroll
            for (int j = 0; j < 4; ++j)
                #pragma unroll
                for (int r = 0; r < 4; ++r) {
                    int row = i * 16 + l4 * 4 + r;
                    int col = j * 16 + l15;
                    *(bf16*)(smem + 65536 + wid * 4096 + row * 128 +
                             (((col >> 3) ^ (row & 7)) * 16) + (col & 7) * 2) =
                        (bf16)s[i][j][r];
                }

        #pragma unroll
        for (int k2 = 0; k2 < 2; ++k2) {
            bf16x8 pa[2];
            #pragma unroll
            for (int i = 0; i < 2; ++i)
                pa[i] = *(const bf16x8*)(smem + 65536 + wid * 4096 +
                    (i * 16 + l15) * 128 + (((k2 * 4 + l4) ^ (l15 & 7)) * 16));
            __builtin_amdgcn_s_setprio(1);
            #pragma unroll
            for (int jd = 0; jd < 8; ++jd) {
                bf16x8 vf = *(const bf16x8*)(Vs + (jd * 16 + l15) * 128 +
                    (((k2 * 4 + l4) ^ (l15 & 7)) * 16));
                o[0][jd] = MFMA(pa[0], vf, o[0][jd]);
                o[1][jd] = MFMA(pa[1], vf, o[1][jd]);
            }
            __builtin_amdgcn_s_setprio(0);
        }
        __syncthreads();
    }

    #pragma unroll
    for (int off = 8; off >= 1; off >>= 1)
        #pragma unroll
        for (int i = 0; i < 2; ++i)
            #pragma unroll
            for (int r = 0; r < 4; ++r) l_run[i][r] += __shfl_xor(l_run[i][r], off);
    #pragma unroll
    for (int i = 0; i < 2; ++i) {
        float inv[4];
        #pragma unroll
        for (int r = 0; r < 4; ++r) inv[r] = 1.0f / fmaxf(l_run[i][r], 1e-30f);
        #pragma unroll
        for (int jd = 0; jd < 8; ++jd)
            #pragma unroll
            for (int r = 0; r < 4; ++r)
                yb[(m0 + wid * 32 + i * 16 + l4 * 4 + r) * 1024 +
                   h * 128 + jd * 16 + l15] = (bf16)(o[i][jd][r] * inv[r]);
    }
}

// ---------------------------------------------------------------- launch
extern "C" void kernel_launch(void* const* d_in, const int* in_sizes, int n_in,
                              void* d_out, int out_size, void* d_ws, size_t ws_size,
                              hipStream_t stream)
{
    (void)in_sizes; (void)n_in; (void)out_size; (void)ws_size;
    const float* x  = (const float*)d_in[0];
    const int* mask = (const int*)d_in[1];
    const float* Wq = (const float*)d_in[2];
    const float* bq = (const float*)d_in[3];
    const float* Wk = (const float*)d_in[4];
    const float* bk = (const float*)d_in[5];
    const float* Wv = (const float*)d_in[6];
    const float* bv = (const float*)d_in[7];
    const float* Wp = (const float*)d_in[8];
    const float* bp = (const float*)d_in[9];
    float* out = (float*)d_out;

    char* ws = (char*)d_ws;
    bf16* xb    = (bf16*)(ws);                      // 16 MB  x bf16 (8192 x 1024)
    bf16* wqkvb = (bf16*)(ws + (16u << 20));        //  6 MB  [Wq;Wk;Wv]
    bf16* wpb   = (bf16*)(ws + (22u << 20));        //  2 MB  Wp
    bf16* qbuf  = (bf16*)(ws + (24u << 20));        // 16 MB  q (scaled)
    bf16* kbuf  = (bf16*)(ws + (40u << 20));        // 16 MB  k
    bf16* vtb   = (bf16*)(ws + (56u << 20));        // 16 MB  v^T per (b,h)
    bf16* ybuf  = (bf16*)(ws + (72u << 20));        // 16 MB  attention out

    convert_kernel<<<6144, 256, 0, stream>>>(x, Wq, Wk, Wv, Wp, xb, wqkvb, wpb);
    gemm2<0, 24><<<1536, 128, 0, stream>>>(xb, wqkvb, bq, bk, bv,
                                           qbuf, kbuf, vtb, nullptr);
    attn_kernel<<<512, 256, 0, stream>>>(qbuf, kbuf, vtb, mask, ybuf);
    gemm2<1, 8><<<512, 128, 0, stream>>>(ybuf, wpb, bp, nullptr, nullptr,
                                         nullptr, nullptr, nullptr, out);
}